// Round 1
// baseline (153.104 us; speedup 1.0000x reference)
//
#include <hip/hip_runtime.h>
#include <hip/hip_bf16.h>

// Confusion-classification criterion:
//   pred = argmax(pred_logits[...,0:2])            (tie -> index 0)
//   class = g==1 ? (pred ? 1 : 2) : (pred ? 3 : 0) (TP=1 FN=2 FP=3 TN=0)
//   loss  = mean over B*N of  -log_softmax(pred_confusion)[class]
//
// Memory-bound: ~117 MB in, 4 B out. One pass, coalesced vector loads,
// hierarchical reduction, one atomicAdd per block.

__global__ __launch_bounds__(256) void confusion_nll_kernel(
    const float2* __restrict__ logits,   // [B*N] pairs
    const float4* __restrict__ conf,     // [B*N] quads
    const int*    __restrict__ tgt,      // [B*N]
    float* __restrict__ out,             // [1], pre-zeroed
    int total)
{
    int idx    = blockIdx.x * blockDim.x + threadIdx.x;
    int stride = gridDim.x * blockDim.x;

    float acc = 0.0f;
    for (int i = idx; i < total; i += stride) {
        float2 l = logits[i];
        float4 c = conf[i];
        int    g = tgt[i];

        // argmax over 2 logits: 1 iff l[1] > l[0] (strict -> first-index tie rule)
        int pred = (l.y > l.x) ? 1 : 0;
        // confusion class
        int cls = (g == 1) ? (pred ? 1 : 2) : (pred ? 3 : 0);

        // stable logsumexp over 4
        float m   = fmaxf(fmaxf(c.x, c.y), fmaxf(c.z, c.w));
        float s   = __expf(c.x - m) + __expf(c.y - m) +
                    __expf(c.z - m) + __expf(c.w - m);
        float lse = m + __logf(s);

        float xc = (cls == 0) ? c.x : (cls == 1) ? c.y : (cls == 2) ? c.z : c.w;
        acc += lse - xc;
    }

    // wave-64 butterfly reduce
    #pragma unroll
    for (int off = 32; off > 0; off >>= 1)
        acc += __shfl_down(acc, off, 64);

    __shared__ float wsum[4];            // 256 threads / 64 lanes = 4 waves
    int lane = threadIdx.x & 63;
    int wid  = threadIdx.x >> 6;
    if (lane == 0) wsum[wid] = acc;
    __syncthreads();

    if (threadIdx.x == 0) {
        float bsum = wsum[0] + wsum[1] + wsum[2] + wsum[3];
        atomicAdd(out, bsum * (1.0f / (float)total));
    }
}

extern "C" void kernel_launch(void* const* d_in, const int* in_sizes, int n_in,
                              void* d_out, int out_size, void* d_ws, size_t ws_size,
                              hipStream_t stream)
{
    const float2* logits = (const float2*)d_in[0];   // [B,N,2] f32
    const float4* conf   = (const float4*)d_in[1];   // [B,N,4] f32
    const int*    tgt    = (const int*)d_in[2];      // [B,N]  int
    float*        out    = (float*)d_out;

    const int total = in_sizes[2];                   // B*N = 4,194,304

    // d_out is poisoned to 0xAA before every timed launch — zero it.
    hipMemsetAsync(out, 0, out_size * sizeof(float), stream);

    // 2048 blocks x 256 threads -> 8 elements/thread via grid-stride.
    const int block = 256;
    const int grid  = 2048;
    confusion_nll_kernel<<<grid, block, 0, stream>>>(logits, conf, tgt, out, total);
}

// Round 2
// 136.665 us; speedup vs baseline: 1.1203x; 1.1203x over previous
//
#include <hip/hip_runtime.h>
#include <hip/hip_bf16.h>

// Confusion-classification criterion (see reference):
//   pred = argmax(pred_logits[...,0:2])            (tie -> index 0)
//   cls  = g==1 ? (pred ? 1 : 2) : (pred ? 3 : 0)  (TP=1 FN=2 FP=3 TN=0)
//   loss = mean over B*N of -log_softmax(pred_confusion)[cls]
//
// Latency-bound fix (R1 -> R2): 4 elements / iteration, all loads 16B
// (float4 / int4), two-kernel reduction so no memset is required.

#define NPART 2048

__device__ __forceinline__ float nll_one(float4 c, bool gpos, bool pred)
{
    int cls = gpos ? (pred ? 1 : 2) : (pred ? 3 : 0);
    float m   = fmaxf(fmaxf(c.x, c.y), fmaxf(c.z, c.w));
    float s   = __expf(c.x - m) + __expf(c.y - m) +
                __expf(c.z - m) + __expf(c.w - m);
    float lse = m + __logf(s);
    float xc  = (cls == 0) ? c.x : (cls == 1) ? c.y : (cls == 2) ? c.z : c.w;
    return lse - xc;
}

__global__ __launch_bounds__(256) void confusion_part_kernel(
    const float4* __restrict__ lg,    // logits as float4: 2 elements each
    const float4* __restrict__ conf,  // confusion rows: 1 element each
    const int4*   __restrict__ tg,    // targets: 4 elements each
    const float2* __restrict__ lg2,   // logits as float2 (tail)
    const float4* __restrict__ conf1, // same as conf (tail alias)
    const int*    __restrict__ tg1,   // targets scalar (tail)
    float* __restrict__ partials,     // [NPART]
    int total)
{
    const int idx    = blockIdx.x * blockDim.x + threadIdx.x;
    const int stride = gridDim.x * blockDim.x;
    const int nvec   = total >> 2;           // groups of 4 elements

    float acc = 0.0f;
    for (int v = idx; v < nvec; v += stride) {
        float4 lA = lg[2 * v];               // elems 4v, 4v+1
        float4 lB = lg[2 * v + 1];           // elems 4v+2, 4v+3
        float4 c0 = conf[4 * v];
        float4 c1 = conf[4 * v + 1];
        float4 c2 = conf[4 * v + 2];
        float4 c3 = conf[4 * v + 3];
        int4   g  = tg[v];

        acc += nll_one(c0, g.x == 1, lA.y > lA.x);
        acc += nll_one(c1, g.y == 1, lA.w > lA.z);
        acc += nll_one(c2, g.z == 1, lB.y > lB.x);
        acc += nll_one(c3, g.w == 1, lB.w > lB.z);
    }

    // scalar tail (total not divisible by 4) — block 0, thread 0 only
    if (blockIdx.x == 0 && threadIdx.x == 0) {
        for (int i = nvec << 2; i < total; ++i) {
            float2 l = lg2[i];
            acc += nll_one(conf1[i], tg1[i] == 1, l.y > l.x);
        }
    }

    // wave-64 reduce
    #pragma unroll
    for (int off = 32; off > 0; off >>= 1)
        acc += __shfl_down(acc, off, 64);

    __shared__ float wsum[4];
    int lane = threadIdx.x & 63;
    int wid  = threadIdx.x >> 6;
    if (lane == 0) wsum[wid] = acc;
    __syncthreads();

    if (threadIdx.x == 0)
        partials[blockIdx.x] = wsum[0] + wsum[1] + wsum[2] + wsum[3];
}

__global__ __launch_bounds__(256) void confusion_final_kernel(
    const float* __restrict__ partials, float* __restrict__ out,
    int npart, float inv_total)
{
    float acc = 0.0f;
    for (int i = threadIdx.x; i < npart; i += 256)
        acc += partials[i];

    #pragma unroll
    for (int off = 32; off > 0; off >>= 1)
        acc += __shfl_down(acc, off, 64);

    __shared__ float wsum[4];
    int lane = threadIdx.x & 63;
    int wid  = threadIdx.x >> 6;
    if (lane == 0) wsum[wid] = acc;
    __syncthreads();

    if (threadIdx.x == 0)
        out[0] = (wsum[0] + wsum[1] + wsum[2] + wsum[3]) * inv_total;
}

extern "C" void kernel_launch(void* const* d_in, const int* in_sizes, int n_in,
                              void* d_out, int out_size, void* d_ws, size_t ws_size,
                              hipStream_t stream)
{
    const float4* lg    = (const float4*)d_in[0];
    const float4* conf  = (const float4*)d_in[1];
    const int4*   tg    = (const int4*)d_in[2];
    const float2* lg2   = (const float2*)d_in[0];
    const int*    tg1   = (const int*)d_in[2];
    float*        out   = (float*)d_out;
    float*        parts = (float*)d_ws;       // NPART floats (8 KB)

    const int total = in_sizes[2];            // B*N = 4,194,304

    confusion_part_kernel<<<NPART, 256, 0, stream>>>(
        lg, conf, tg, lg2, conf, tg1, parts, total);
    confusion_final_kernel<<<1, 256, 0, stream>>>(
        parts, out, NPART, 1.0f / (float)total);
}